// Round 11
// baseline (316.332 us; speedup 1.0000x reference)
//
#include <hip/hip_runtime.h>

namespace {
constexpr int kB = 16;
constexpr int kN = 131072;            // 2^17
constexpr int kNLog = 17;
constexpr int kCMid = 128;
constexpr int kCOut = 16;
constexpr int kCells32Log = 15;       // 32^3
constexpr int kCells64Log = 18;       // 64^3
constexpr int kCells32 = 1 << kCells32Log;
constexpr int kCells64 = 1 << kCells64Log;
constexpr long kOut32Elems = (long)kB * kCOut * kCells32;
constexpr int kChunks32 = 16;         // natural point-chunks per batch (win32)
constexpr int kSlabs64 = 8;           // cell slabs per batch (win64)
constexpr int kSlabCells = kCells64 / kSlabs64;  // 32768 (u32 -> 128KB LDS)
}  // namespace

typedef __bf16 bf16x8 __attribute__((ext_vector_type(8)));
typedef float f32x4 __attribute__((ext_vector_type(4)));

__device__ inline unsigned int packbf2(float lo, float hi) {
    // RNE-round both to bf16, pack (hi<<16)|lo.
    unsigned int a = __float_as_uint(lo);
    unsigned int b = __float_as_uint(hi);
    a = (a + 0x7FFFu + ((a >> 16) & 1u)) >> 16;
    b = (b + 0x7FFFu + ((b >> 16) & 1u)) & 0xFFFF0000u;
    return b | a;
}
__device__ inline float bf_lo(unsigned int p) { return __uint_as_float(p << 16); }
__device__ inline float bf_hi(unsigned int p) { return __uint_as_float(p & 0xFFFF0000u); }

__device__ inline uint4 pack8(const float* h) {
    uint4 r;
    r.x = packbf2(h[0], h[1]); r.y = packbf2(h[2], h[3]);
    r.z = packbf2(h[4], h[5]); r.w = packbf2(h[6], h[7]);
    return r;
}

// ---------------------------------------------------------------------------
// Stage packed weights:
//  W1p[k][4]  = (w0,w1,w2,b1k)                         (f32, 2 KB)
//  w2h/w2l[kw*64+lane] = A-fragment of W2 for MFMA 16x16x32, bf16 hi/lo split.
// ---------------------------------------------------------------------------
__global__ __launch_bounds__(256) void k_pack(
    const float* __restrict__ W1, const float* __restrict__ b1,
    const float* __restrict__ W2,
    float* __restrict__ W1p, uint4* __restrict__ w2h, uint4* __restrict__ w2l)
{
    const int t = threadIdx.x;
    for (int k = t; k < kCMid; k += 256) {
        W1p[k * 4 + 0] = W1[k * 3 + 0];
        W1p[k * 4 + 1] = W1[k * 3 + 1];
        W1p[k * 4 + 2] = W1[k * 3 + 2];
        W1p[k * 4 + 3] = b1[k];
    }
    {
        const int kw = t >> 6;
        const int lane = t & 63;
        const int ch = lane & 15;
        const int grp = lane >> 4;
        float v[8], lo[8];
        #pragma unroll
        for (int e = 0; e < 8; ++e)
            v[e] = W2[ch * kCMid + kw * 32 + grp * 8 + e];
        const uint4 hh = pack8(v);
        lo[0] = v[0] - bf_lo(hh.x); lo[1] = v[1] - bf_hi(hh.x);
        lo[2] = v[2] - bf_lo(hh.y); lo[3] = v[3] - bf_hi(hh.y);
        lo[4] = v[4] - bf_lo(hh.z); lo[5] = v[5] - bf_hi(hh.z);
        lo[6] = v[6] - bf_lo(hh.w); lo[7] = v[7] - bf_hi(hh.w);
        w2h[t] = hh;
        w2l[t] = pack8(lo);
    }
}

// ---------------------------------------------------------------------------
// Prep pass (replaces k_prec): two independent jobs on the same gid space.
//  (a) permuted-order: inv[b][perm[b][i]] = i  (bijective scatter, no atomics)
//  (b) natural-order:  cell64[b][gid] from x (coalesced read+write).
// Cell math: __fmul_rn/__fadd_rn (no FMA contraction) matches numpy exactly.
// ---------------------------------------------------------------------------
__global__ __launch_bounds__(256) void k_prep(
    const float* __restrict__ x,
    const int* __restrict__ perm,
    int* __restrict__ inv,
    unsigned int* __restrict__ cell64)
{
    const long gid = (long)blockIdx.x * 256 + threadIdx.x;  // over B*N
    const long bbase = gid & ~(long)(kN - 1);               // b*kN
    const int i = (int)(gid & (kN - 1));
    const int j = perm[gid];
    inv[bbase + j] = i;

    const float v0 = x[gid * 3 + 0];
    const float v1 = x[gid * 3 + 1];
    const float v2 = x[gid * 3 + 2];
    const int ix64 = (int)fminf(fmaxf(__fadd_rn(__fmul_rn(v0, 64.0f), 32.5f), 0.0f), 63.0f);
    const int iy64 = (int)fminf(fmaxf(__fadd_rn(__fmul_rn(v1, 64.0f), 32.5f), 0.0f), 63.0f);
    const int iz64 = (int)fminf(fmaxf(__fadd_rn(__fmul_rn(v2, 64.0f), 32.5f), 0.0f), 63.0f);
    cell64[gid] = (unsigned int)((ix64 * 64 + iy64) * 64 + iz64);
}

// ---------------------------------------------------------------------------
// MFMA MLP, natural order (unchanged from R10 -- verified passing).
// ---------------------------------------------------------------------------
__global__ __launch_bounds__(256, 4) void k_mlp(
    const float* __restrict__ x,
    const float* __restrict__ W1p,
    const uint4* __restrict__ w2h, const uint4* __restrict__ w2l,
    const float* __restrict__ b2,
    uint2* __restrict__ feat)          // 4 uint2 per point (16 bf16)
{
    const int tid = threadIdx.x;
    const int lane = tid & 63;
    const int grp = lane >> 4;          // 0..3
    const int pt16 = lane & 15;
    const long base = (((long)blockIdx.x << 2) + (tid >> 6)) << 6;  // wave*64

    float xv[4][3];
    #pragma unroll
    for (int t = 0; t < 4; ++t) {
        const float* xp = x + (base + t * 16 + pt16) * 3;
        xv[t][0] = xp[0]; xv[t][1] = xp[1]; xv[t][2] = xp[2];
    }

    f32x4 acc[4];
    #pragma unroll
    for (int t = 0; t < 4; ++t) acc[t] = (f32x4){0.f, 0.f, 0.f, 0.f};

    const float4* __restrict__ w1v = (const float4*)W1p;

    #pragma unroll
    for (int kw = 0; kw < 4; ++kw) {
        const bf16x8 ah = __builtin_bit_cast(bf16x8, w2h[(kw << 6) + lane]);
        const bf16x8 al = __builtin_bit_cast(bf16x8, w2l[(kw << 6) + lane]);
        float4 w1r[8];
        #pragma unroll
        for (int e = 0; e < 8; ++e)
            w1r[e] = w1v[(kw << 5) + (grp << 3) + e];

        #pragma unroll
        for (int t = 0; t < 4; ++t) {
            float h[8], lo[8];
            #pragma unroll
            for (int e = 0; e < 8; ++e)
                h[e] = fmaxf(fmaf(w1r[e].x, xv[t][0],
                              fmaf(w1r[e].y, xv[t][1],
                               fmaf(w1r[e].z, xv[t][2], w1r[e].w))), 0.0f);
            const uint4 bh = pack8(h);
            lo[0] = h[0] - bf_lo(bh.x); lo[1] = h[1] - bf_hi(bh.x);
            lo[2] = h[2] - bf_lo(bh.y); lo[3] = h[3] - bf_hi(bh.y);
            lo[4] = h[4] - bf_lo(bh.z); lo[5] = h[5] - bf_hi(bh.z);
            lo[6] = h[6] - bf_lo(bh.w); lo[7] = h[7] - bf_hi(bh.w);
            const uint4 bl4 = pack8(lo);
            const bf16x8 bhv = __builtin_bit_cast(bf16x8, bh);
            const bf16x8 blv = __builtin_bit_cast(bf16x8, bl4);
            acc[t] = __builtin_amdgcn_mfma_f32_16x16x32_bf16(ah, bhv, acc[t], 0, 0, 0);
            acc[t] = __builtin_amdgcn_mfma_f32_16x16x32_bf16(ah, blv, acc[t], 0, 0, 0);
            acc[t] = __builtin_amdgcn_mfma_f32_16x16x32_bf16(al, bhv, acc[t], 0, 0, 0);
        }
    }

    const float4 bias = ((const float4*)b2)[grp];
    #pragma unroll
    for (int t = 0; t < 4; ++t) {
        const float c0 = acc[t][0] + bias.x;
        const float c1 = acc[t][1] + bias.y;
        const float c2 = acc[t][2] + bias.z;
        const float c3 = acc[t][3] + bias.w;
        uint2 o;
        o.x = packbf2(c0, c1);
        o.y = packbf2(c2, c3);
        feat[((base + t * 16 + pt16) << 2) + grp] = o;
    }
}

// ---------------------------------------------------------------------------
// win32 via LDS: block = (batch b, NATURAL point-chunk c). All reads
// coalesced (x 12B/pt + inv 4B/pt), cell32 computed inline with exact math.
// Full 32768-cell u32 pri array in 128 KB LDS; ds-atomicMax; coalesced
// partial writeout. Merge happens inline in k_gather32.
// ---------------------------------------------------------------------------
__global__ __launch_bounds__(1024) void k_win32(
    const float* __restrict__ x,
    const int* __restrict__ inv,
    unsigned int* __restrict__ partial32)
{
    __shared__ unsigned int lwin[kCells32];   // 128 KB
    const int b = blockIdx.x >> 4;
    const int c = blockIdx.x & (kChunks32 - 1);
    const int t = threadIdx.x;

    #pragma unroll
    for (int r = 0; r < kCells32 / 1024; ++r) lwin[r * 1024 + t] = 0u;
    __syncthreads();

    const long base = ((long)b << kNLog) + (long)c * (kN / kChunks32);
    #pragma unroll
    for (int r = 0; r < (kN / kChunks32) / 1024; ++r) {   // 8 iters
        const long j = base + r * 1024 + t;
        const float v0 = x[j * 3 + 0];
        const float v1 = x[j * 3 + 1];
        const float v2 = x[j * 3 + 2];
        const int ix = (int)fminf(fmaxf(__fadd_rn(__fmul_rn(v0, 32.0f), 16.5f), 0.0f), 31.0f);
        const int iy = (int)fminf(fmaxf(__fadd_rn(__fmul_rn(v1, 32.0f), 16.5f), 0.0f), 31.0f);
        const int iz = (int)fminf(fmaxf(__fadd_rn(__fmul_rn(v2, 32.0f), 16.5f), 0.0f), 31.0f);
        const unsigned int pri = (unsigned int)(inv[j] + 1);
        atomicMax(&lwin[(ix * 32 + iy) * 32 + iz], pri);
    }
    __syncthreads();

    unsigned int* dst = partial32 + ((long)blockIdx.x << kCells32Log);
    #pragma unroll
    for (int r = 0; r < kCells32 / 1024; ++r) dst[r * 1024 + t] = lwin[r * 1024 + t];
}

// ---------------------------------------------------------------------------
// win64 via LDS slabs, u32 pri tokens (j recovered later via perm[b,pri-1]):
// 32768-cell slabs -> 8 slabs/batch (half of R10's 16 -> half the rescan).
// Block scans its batch's cell64+inv (1 MB coalesced), filters to its slab,
// LDS-atomics, exclusive coalesced writeout. No global atomics, no zeroing.
// ---------------------------------------------------------------------------
__global__ __launch_bounds__(1024) void k_win64(
    const unsigned int* __restrict__ cell64,
    const int* __restrict__ inv,
    unsigned int* __restrict__ win64p)
{
    __shared__ unsigned int lwin[kSlabCells];   // 128 KB
    const int b = blockIdx.x >> 3;
    const int s = blockIdx.x & (kSlabs64 - 1);
    const int t = threadIdx.x;

    #pragma unroll
    for (int r = 0; r < kSlabCells / 1024; ++r) lwin[r * 1024 + t] = 0u;
    __syncthreads();

    const long base = (long)b << kNLog;
    for (int r = 0; r < kN / 1024; ++r) {             // 128 iters
        const long j = base + r * 1024 + t;
        const unsigned int cell = cell64[j];
        const unsigned int pri = (unsigned int)(inv[j] + 1);
        if ((int)(cell >> 15) == s)
            atomicMax(&lwin[cell & (kSlabCells - 1)], pri);
    }
    __syncthreads();

    unsigned int* dst = win64p + ((long)b << kCells64Log) + ((long)s << 15);
    #pragma unroll
    for (int r = 0; r < kSlabCells / 1024; ++r) dst[r * 1024 + t] = lwin[r * 1024 + t];
}

// ---------------------------------------------------------------------------
// gather32 with inline 16-way partial merge: w = max_c partial32[b][c][cell];
// i = w-1 -> j = perm[b,i] (L2 hop) -> feat[b,j]. Full rewrite every call.
// ---------------------------------------------------------------------------
__global__ __launch_bounds__(256) void k_gather32(
    const unsigned int* __restrict__ partial32,
    const int* __restrict__ perm,
    const uint4* __restrict__ feat,
    float* __restrict__ out)
{
    const long gid = (long)blockIdx.x * 256 + threadIdx.x;  // over B*cells32
    const int b = (int)(gid >> kCells32Log);
    const int cell = (int)(gid & (kCells32 - 1));

    unsigned int w = 0u;
    #pragma unroll
    for (int c = 0; c < kChunks32; ++c)
        w = max(w, partial32[(((long)(b * kChunks32 + c)) << kCells32Log) + cell]);

    float v[kCOut];
    #pragma unroll
    for (int c = 0; c < kCOut; ++c) v[c] = 0.0f;

    if (w != 0u) {
        const int i = (int)(w - 1u);
        const int j = perm[((long)b << kNLog) + i];
        const long pidx = ((long)b << kNLog) + j;
        const uint4 f0 = feat[pidx * 2 + 0];
        const uint4 f1 = feat[pidx * 2 + 1];
        v[0]  = bf_lo(f0.x); v[1]  = bf_hi(f0.x);
        v[2]  = bf_lo(f0.y); v[3]  = bf_hi(f0.y);
        v[4]  = bf_lo(f0.z); v[5]  = bf_hi(f0.z);
        v[6]  = bf_lo(f0.w); v[7]  = bf_hi(f0.w);
        v[8]  = bf_lo(f1.x); v[9]  = bf_hi(f1.x);
        v[10] = bf_lo(f1.y); v[11] = bf_hi(f1.y);
        v[12] = bf_lo(f1.z); v[13] = bf_hi(f1.z);
        v[14] = bf_lo(f1.w); v[15] = bf_hi(f1.w);
    }

    float* op = out + (((long)b * kCOut) << kCells32Log) + cell;
    #pragma unroll
    for (int c = 0; c < kCOut; ++c) op[(long)c << kCells32Log] = v[c];
}

// ---------------------------------------------------------------------------
// gather64: u32 pri token (coalesced, half the bytes of R10's u64) ->
// j = perm[b,pri-1] (random 4B into L2-hot 512KB/batch) -> feat[b,j]
// (random 32B, L3) -> write 16 channels (zeros if empty).
// ---------------------------------------------------------------------------
__global__ __launch_bounds__(256) void k_gather64(
    const unsigned int* __restrict__ win,
    const int* __restrict__ perm,
    const uint4* __restrict__ feat,
    float* __restrict__ out)
{
    const long gid = (long)blockIdx.x * 256 + threadIdx.x;  // over B*cells64
    const int b = (int)(gid >> kCells64Log);
    const int cell = (int)(gid & (kCells64 - 1));
    const unsigned int w = win[gid];

    float v[kCOut];
    #pragma unroll
    for (int c = 0; c < kCOut; ++c) v[c] = 0.0f;

    if (w != 0u) {
        const int i = (int)(w - 1u);
        const int j = perm[((long)b << kNLog) + i];
        const long pidx = ((long)b << kNLog) + j;
        const uint4 f0 = feat[pidx * 2 + 0];
        const uint4 f1 = feat[pidx * 2 + 1];
        v[0]  = bf_lo(f0.x); v[1]  = bf_hi(f0.x);
        v[2]  = bf_lo(f0.y); v[3]  = bf_hi(f0.y);
        v[4]  = bf_lo(f0.z); v[5]  = bf_hi(f0.z);
        v[6]  = bf_lo(f0.w); v[7]  = bf_hi(f0.w);
        v[8]  = bf_lo(f1.x); v[9]  = bf_hi(f1.x);
        v[10] = bf_lo(f1.y); v[11] = bf_hi(f1.y);
        v[12] = bf_lo(f1.z); v[13] = bf_hi(f1.z);
        v[14] = bf_lo(f1.w); v[15] = bf_hi(f1.w);
    }

    float* op = out + (((long)b * kCOut) << kCells64Log) + cell;
    #pragma unroll
    for (int c = 0; c < kCOut; ++c) op[(long)c << kCells64Log] = v[c];
}

extern "C" void kernel_launch(void* const* d_in, const int* in_sizes, int n_in,
                              void* d_out, int out_size, void* d_ws, size_t ws_size,
                              hipStream_t stream)
{
    const float* x  = (const float*)d_in[0];
    const float* W1 = (const float*)d_in[1];
    const float* b1 = (const float*)d_in[2];
    const float* W2 = (const float*)d_in[3];
    const float* b2 = (const float*)d_in[4];
    const int* perm = (const int*)d_in[5];

    float* out32 = (float*)d_out;
    float* out64 = out32 + kOut32Elems;

    // ws layout:
    //  [W1p 2KB][w2h 4KB][w2l 4KB][pad->16KB]
    //  [inv 8.4MB][cell64 8.4MB][partial32 32MB][win64p 16.8MB][feat 67MB]
    //  total ~133 MB
    float* W1p = (float*)d_ws;
    uint4* w2h = (uint4*)((char*)d_ws + 2048);
    uint4* w2l = w2h + 256;
    int* inv = (int*)((char*)d_ws + 16384);
    unsigned int* cell64 = (unsigned int*)(inv + (size_t)kB * kN);
    unsigned int* partial32 = cell64 + (size_t)kB * kN;
    unsigned int* win64p = partial32 + (size_t)kB * kChunks32 * kCells32;
    uint4* feat = (uint4*)(win64p + (size_t)kB * kCells64);

    const int nPtsBlocks = (int)(((long)kB * kN) / 256);        // 8192
    const int n32Blocks  = (int)(((long)kB * kCells32) / 256);  // 2048
    const int n64Blocks  = (int)(((long)kB * kCells64) / 256);  // 16384
    dim3 blk(256);

    k_pack<<<1, 256, 0, stream>>>(W1, b1, W2, W1p, w2h, w2l);
    k_prep<<<nPtsBlocks, blk, 0, stream>>>(x, perm, inv, cell64);
    k_mlp<<<nPtsBlocks, blk, 0, stream>>>(x, W1p, w2h, w2l, b2, (uint2*)feat);

    k_win32<<<kB * kChunks32, 1024, 0, stream>>>(x, inv, partial32);
    k_win64<<<kB * kSlabs64, 1024, 0, stream>>>(cell64, inv, win64p);

    k_gather32<<<n32Blocks, blk, 0, stream>>>(partial32, perm, feat, out32);
    k_gather64<<<n64Blocks, blk, 0, stream>>>(win64p, perm, feat, out64);
}

// Round 12
// 301.382 us; speedup vs baseline: 1.0496x; 1.0496x over previous
//
#include <hip/hip_runtime.h>

namespace {
constexpr int kB = 16;
constexpr int kN = 131072;            // 2^17
constexpr int kNLog = 17;
constexpr int kCMid = 128;
constexpr int kCOut = 16;
constexpr int kCells32Log = 15;       // 32^3
constexpr int kCells64Log = 18;       // 64^3
constexpr int kCells32 = 1 << kCells32Log;
constexpr int kCells64 = 1 << kCells64Log;
constexpr long kOut32Elems = (long)kB * kCOut * kCells32;
constexpr int kChunks32 = 16;         // natural point-chunks per batch (win32)
constexpr int kSlabs64 = 16;          // cell slabs per batch (win64)
constexpr int kSlabCells = kCells64 / kSlabs64;  // 16384 (u64 -> 128KB LDS)
}  // namespace

typedef __bf16 bf16x8 __attribute__((ext_vector_type(8)));
typedef float f32x4 __attribute__((ext_vector_type(4)));

__device__ inline unsigned int packbf2(float lo, float hi) {
    // RNE-round both to bf16, pack (hi<<16)|lo.
    unsigned int a = __float_as_uint(lo);
    unsigned int b = __float_as_uint(hi);
    a = (a + 0x7FFFu + ((a >> 16) & 1u)) >> 16;
    b = (b + 0x7FFFu + ((b >> 16) & 1u)) & 0xFFFF0000u;
    return b | a;
}
__device__ inline float bf_lo(unsigned int p) { return __uint_as_float(p << 16); }
__device__ inline float bf_hi(unsigned int p) { return __uint_as_float(p & 0xFFFF0000u); }

__device__ inline uint4 pack8(const float* h) {
    uint4 r;
    r.x = packbf2(h[0], h[1]); r.y = packbf2(h[2], h[3]);
    r.z = packbf2(h[4], h[5]); r.w = packbf2(h[6], h[7]);
    return r;
}

// ---------------------------------------------------------------------------
// Stage packed weights: W1p[k][4]=(w0,w1,w2,b1k); w2h/w2l = MFMA A-fragment
// of W2 (bf16 hi/lo split). Verified R10.
// ---------------------------------------------------------------------------
__global__ __launch_bounds__(256) void k_pack(
    const float* __restrict__ W1, const float* __restrict__ b1,
    const float* __restrict__ W2,
    float* __restrict__ W1p, uint4* __restrict__ w2h, uint4* __restrict__ w2l)
{
    const int t = threadIdx.x;
    for (int k = t; k < kCMid; k += 256) {
        W1p[k * 4 + 0] = W1[k * 3 + 0];
        W1p[k * 4 + 1] = W1[k * 3 + 1];
        W1p[k * 4 + 2] = W1[k * 3 + 2];
        W1p[k * 4 + 3] = b1[k];
    }
    {
        const int kw = t >> 6;
        const int lane = t & 63;
        const int ch = lane & 15;
        const int grp = lane >> 4;
        float v[8], lo[8];
        #pragma unroll
        for (int e = 0; e < 8; ++e)
            v[e] = W2[ch * kCMid + kw * 32 + grp * 8 + e];
        const uint4 hh = pack8(v);
        lo[0] = v[0] - bf_lo(hh.x); lo[1] = v[1] - bf_hi(hh.x);
        lo[2] = v[2] - bf_lo(hh.y); lo[3] = v[3] - bf_hi(hh.y);
        lo[4] = v[4] - bf_lo(hh.z); lo[5] = v[5] - bf_hi(hh.z);
        lo[6] = v[6] - bf_lo(hh.w); lo[7] = v[7] - bf_hi(hh.w);
        w2h[t] = hh;
        w2l[t] = pack8(lo);
    }
}

// ---------------------------------------------------------------------------
// Prep: (a) inv[b][perm[i]]=i (bijective scatter); (b) cell64[b][j] coalesced.
// Cell math: __fmul_rn/__fadd_rn (no FMA contraction) matches numpy exactly.
// ---------------------------------------------------------------------------
__global__ __launch_bounds__(256) void k_prep(
    const float* __restrict__ x,
    const int* __restrict__ perm,
    int* __restrict__ inv,
    unsigned int* __restrict__ cell64)
{
    const long gid = (long)blockIdx.x * 256 + threadIdx.x;  // over B*N
    const long bbase = gid & ~(long)(kN - 1);               // b*kN
    const int i = (int)(gid & (kN - 1));
    const int j = perm[gid];
    inv[bbase + j] = i;

    const float v0 = x[gid * 3 + 0];
    const float v1 = x[gid * 3 + 1];
    const float v2 = x[gid * 3 + 2];
    const int ix64 = (int)fminf(fmaxf(__fadd_rn(__fmul_rn(v0, 64.0f), 32.5f), 0.0f), 63.0f);
    const int iy64 = (int)fminf(fmaxf(__fadd_rn(__fmul_rn(v1, 64.0f), 32.5f), 0.0f), 63.0f);
    const int iz64 = (int)fminf(fmaxf(__fadd_rn(__fmul_rn(v2, 64.0f), 32.5f), 0.0f), 63.0f);
    cell64[gid] = (unsigned int)((ix64 * 64 + iy64) * 64 + iz64);
}

// ---------------------------------------------------------------------------
// MFMA MLP, natural order (verified R10/R11, unchanged).
// ---------------------------------------------------------------------------
__global__ __launch_bounds__(256, 4) void k_mlp(
    const float* __restrict__ x,
    const float* __restrict__ W1p,
    const uint4* __restrict__ w2h, const uint4* __restrict__ w2l,
    const float* __restrict__ b2,
    uint2* __restrict__ feat)          // 4 uint2 per point (16 bf16)
{
    const int tid = threadIdx.x;
    const int lane = tid & 63;
    const int grp = lane >> 4;          // 0..3
    const int pt16 = lane & 15;
    const long base = (((long)blockIdx.x << 2) + (tid >> 6)) << 6;  // wave*64

    float xv[4][3];
    #pragma unroll
    for (int t = 0; t < 4; ++t) {
        const float* xp = x + (base + t * 16 + pt16) * 3;
        xv[t][0] = xp[0]; xv[t][1] = xp[1]; xv[t][2] = xp[2];
    }

    f32x4 acc[4];
    #pragma unroll
    for (int t = 0; t < 4; ++t) acc[t] = (f32x4){0.f, 0.f, 0.f, 0.f};

    const float4* __restrict__ w1v = (const float4*)W1p;

    #pragma unroll
    for (int kw = 0; kw < 4; ++kw) {
        const bf16x8 ah = __builtin_bit_cast(bf16x8, w2h[(kw << 6) + lane]);
        const bf16x8 al = __builtin_bit_cast(bf16x8, w2l[(kw << 6) + lane]);
        float4 w1r[8];
        #pragma unroll
        for (int e = 0; e < 8; ++e)
            w1r[e] = w1v[(kw << 5) + (grp << 3) + e];

        #pragma unroll
        for (int t = 0; t < 4; ++t) {
            float h[8], lo[8];
            #pragma unroll
            for (int e = 0; e < 8; ++e)
                h[e] = fmaxf(fmaf(w1r[e].x, xv[t][0],
                              fmaf(w1r[e].y, xv[t][1],
                               fmaf(w1r[e].z, xv[t][2], w1r[e].w))), 0.0f);
            const uint4 bh = pack8(h);
            lo[0] = h[0] - bf_lo(bh.x); lo[1] = h[1] - bf_hi(bh.x);
            lo[2] = h[2] - bf_lo(bh.y); lo[3] = h[3] - bf_hi(bh.y);
            lo[4] = h[4] - bf_lo(bh.z); lo[5] = h[5] - bf_hi(bh.z);
            lo[6] = h[6] - bf_lo(bh.w); lo[7] = h[7] - bf_hi(bh.w);
            const uint4 bl4 = pack8(lo);
            const bf16x8 bhv = __builtin_bit_cast(bf16x8, bh);
            const bf16x8 blv = __builtin_bit_cast(bf16x8, bl4);
            acc[t] = __builtin_amdgcn_mfma_f32_16x16x32_bf16(ah, bhv, acc[t], 0, 0, 0);
            acc[t] = __builtin_amdgcn_mfma_f32_16x16x32_bf16(ah, blv, acc[t], 0, 0, 0);
            acc[t] = __builtin_amdgcn_mfma_f32_16x16x32_bf16(al, bhv, acc[t], 0, 0, 0);
        }
    }

    const float4 bias = ((const float4*)b2)[grp];
    #pragma unroll
    for (int t = 0; t < 4; ++t) {
        const float c0 = acc[t][0] + bias.x;
        const float c1 = acc[t][1] + bias.y;
        const float c2 = acc[t][2] + bias.z;
        const float c3 = acc[t][3] + bias.w;
        uint2 o;
        o.x = packbf2(c0, c1);
        o.y = packbf2(c2, c3);
        feat[((base + t * 16 + pt16) << 2) + grp] = o;
    }
}

// ---------------------------------------------------------------------------
// win32 via LDS (verified R11): block = (batch, natural point-chunk), all
// reads coalesced, full 32768-cell u32 pri array in 128 KB LDS, partial
// writeout; merge inline in k_gather32.
// ---------------------------------------------------------------------------
__global__ __launch_bounds__(1024) void k_win32(
    const float* __restrict__ x,
    const int* __restrict__ inv,
    unsigned int* __restrict__ partial32)
{
    __shared__ unsigned int lwin[kCells32];   // 128 KB
    const int b = blockIdx.x >> 4;
    const int c = blockIdx.x & (kChunks32 - 1);
    const int t = threadIdx.x;

    #pragma unroll
    for (int r = 0; r < kCells32 / 1024; ++r) lwin[r * 1024 + t] = 0u;
    __syncthreads();

    const long base = ((long)b << kNLog) + (long)c * (kN / kChunks32);
    #pragma unroll
    for (int r = 0; r < (kN / kChunks32) / 1024; ++r) {   // 8 iters
        const long j = base + r * 1024 + t;
        const float v0 = x[j * 3 + 0];
        const float v1 = x[j * 3 + 1];
        const float v2 = x[j * 3 + 2];
        const int ix = (int)fminf(fmaxf(__fadd_rn(__fmul_rn(v0, 32.0f), 16.5f), 0.0f), 31.0f);
        const int iy = (int)fminf(fmaxf(__fadd_rn(__fmul_rn(v1, 32.0f), 16.5f), 0.0f), 31.0f);
        const int iz = (int)fminf(fmaxf(__fadd_rn(__fmul_rn(v2, 32.0f), 16.5f), 0.0f), 31.0f);
        const unsigned int pri = (unsigned int)(inv[j] + 1);
        atomicMax(&lwin[(ix * 32 + iy) * 32 + iz], pri);
    }
    __syncthreads();

    unsigned int* dst = partial32 + ((long)blockIdx.x << kCells32Log);
    #pragma unroll
    for (int r = 0; r < kCells32 / 1024; ++r) dst[r * 1024 + t] = lwin[r * 1024 + t];
}

// ---------------------------------------------------------------------------
// win64 + out64 FUSED: block = (batch b, slab s of 16384 cells). u64 tokens
// (pri<<32)|j in 128 KB LDS (j natural -> no perm hop, R11 lesson); 16
// slabs/batch = 256 blocks = full chip (R11's 8-slab used half). Scan
// cell64+inv coalesced (1MB/block); then gather feat per winner and write
// out64 DIRECTLY (saves the 33.5MB win64 write + 33.5MB read + a launch).
// Writes all 16 channels incl. zeros for empties (full rewrite per call).
// ---------------------------------------------------------------------------
__global__ __launch_bounds__(1024) void k_win64_out(
    const unsigned int* __restrict__ cell64,
    const int* __restrict__ inv,
    const uint4* __restrict__ feat,
    float* __restrict__ out64)
{
    __shared__ unsigned long long lwin[kSlabCells];   // 128 KB
    const int b = blockIdx.x >> 4;
    const int s = blockIdx.x & (kSlabs64 - 1);
    const int t = threadIdx.x;

    #pragma unroll
    for (int r = 0; r < kSlabCells / 1024; ++r) lwin[r * 1024 + t] = 0ull;
    __syncthreads();

    const long base = (long)b << kNLog;
    for (int r = 0; r < kN / 1024; ++r) {             // 128 iters
        const int j = r * 1024 + t;
        const unsigned int cell = cell64[base + j];
        const unsigned long long pri = (unsigned long long)(inv[base + j] + 1);
        if ((int)(cell >> 14) == s)
            atomicMax(&lwin[(int)(cell & (kSlabCells - 1))],
                      (pri << 32) | (unsigned int)j);
    }
    __syncthreads();

    const long obase = ((long)b * kCOut) << kCells64Log;
    #pragma unroll 2
    for (int r = 0; r < kSlabCells / 1024; ++r) {     // 16 iters
        const int cl = r * 1024 + t;
        const unsigned long long w = lwin[cl];

        float v[kCOut];
        #pragma unroll
        for (int c = 0; c < kCOut; ++c) v[c] = 0.0f;

        if (w != 0ull) {
            const long pidx = base + (int)(w & 0xFFFFFFFFull);
            const uint4 f0 = feat[pidx * 2 + 0];
            const uint4 f1 = feat[pidx * 2 + 1];
            v[0]  = bf_lo(f0.x); v[1]  = bf_hi(f0.x);
            v[2]  = bf_lo(f0.y); v[3]  = bf_hi(f0.y);
            v[4]  = bf_lo(f0.z); v[5]  = bf_hi(f0.z);
            v[6]  = bf_lo(f0.w); v[7]  = bf_hi(f0.w);
            v[8]  = bf_lo(f1.x); v[9]  = bf_hi(f1.x);
            v[10] = bf_lo(f1.y); v[11] = bf_hi(f1.y);
            v[12] = bf_lo(f1.z); v[13] = bf_hi(f1.z);
            v[14] = bf_lo(f1.w); v[15] = bf_hi(f1.w);
        }

        const int cell = (s << 14) + cl;
        float* op = out64 + obase + cell;
        #pragma unroll
        for (int c = 0; c < kCOut; ++c) op[(long)c << kCells64Log] = v[c];
    }
}

// ---------------------------------------------------------------------------
// gather32 with inline 16-way partial merge (verified R11): w = max partials;
// i = w-1 -> j = perm[b,i] (L2 hop) -> feat[b,j]. Full rewrite every call.
// ---------------------------------------------------------------------------
__global__ __launch_bounds__(256) void k_gather32(
    const unsigned int* __restrict__ partial32,
    const int* __restrict__ perm,
    const uint4* __restrict__ feat,
    float* __restrict__ out)
{
    const long gid = (long)blockIdx.x * 256 + threadIdx.x;  // over B*cells32
    const int b = (int)(gid >> kCells32Log);
    const int cell = (int)(gid & (kCells32 - 1));

    unsigned int w = 0u;
    #pragma unroll
    for (int c = 0; c < kChunks32; ++c)
        w = max(w, partial32[(((long)(b * kChunks32 + c)) << kCells32Log) + cell]);

    float v[kCOut];
    #pragma unroll
    for (int c = 0; c < kCOut; ++c) v[c] = 0.0f;

    if (w != 0u) {
        const int i = (int)(w - 1u);
        const int j = perm[((long)b << kNLog) + i];
        const long pidx = ((long)b << kNLog) + j;
        const uint4 f0 = feat[pidx * 2 + 0];
        const uint4 f1 = feat[pidx * 2 + 1];
        v[0]  = bf_lo(f0.x); v[1]  = bf_hi(f0.x);
        v[2]  = bf_lo(f0.y); v[3]  = bf_hi(f0.y);
        v[4]  = bf_lo(f0.z); v[5]  = bf_hi(f0.z);
        v[6]  = bf_lo(f0.w); v[7]  = bf_hi(f0.w);
        v[8]  = bf_lo(f1.x); v[9]  = bf_hi(f1.x);
        v[10] = bf_lo(f1.y); v[11] = bf_hi(f1.y);
        v[12] = bf_lo(f1.z); v[13] = bf_hi(f1.z);
        v[14] = bf_lo(f1.w); v[15] = bf_hi(f1.w);
    }

    float* op = out + (((long)b * kCOut) << kCells32Log) + cell;
    #pragma unroll
    for (int c = 0; c < kCOut; ++c) op[(long)c << kCells32Log] = v[c];
}

extern "C" void kernel_launch(void* const* d_in, const int* in_sizes, int n_in,
                              void* d_out, int out_size, void* d_ws, size_t ws_size,
                              hipStream_t stream)
{
    const float* x  = (const float*)d_in[0];
    const float* W1 = (const float*)d_in[1];
    const float* b1 = (const float*)d_in[2];
    const float* W2 = (const float*)d_in[3];
    const float* b2 = (const float*)d_in[4];
    const int* perm = (const int*)d_in[5];

    float* out32 = (float*)d_out;
    float* out64 = out32 + kOut32Elems;

    // ws layout:
    //  [W1p 2KB][w2h 4KB][w2l 4KB][pad->16KB]
    //  [inv 8.4MB][cell64 8.4MB][partial32 32MB][feat 67MB]   total ~116 MB
    float* W1p = (float*)d_ws;
    uint4* w2h = (uint4*)((char*)d_ws + 2048);
    uint4* w2l = w2h + 256;
    int* inv = (int*)((char*)d_ws + 16384);
    unsigned int* cell64 = (unsigned int*)(inv + (size_t)kB * kN);
    unsigned int* partial32 = cell64 + (size_t)kB * kN;
    uint4* feat = (uint4*)(partial32 + (size_t)kB * kChunks32 * kCells32);

    const int nPtsBlocks = (int)(((long)kB * kN) / 256);        // 8192
    const int n32Blocks  = (int)(((long)kB * kCells32) / 256);  // 2048
    dim3 blk(256);

    k_pack<<<1, 256, 0, stream>>>(W1, b1, W2, W1p, w2h, w2l);
    k_prep<<<nPtsBlocks, blk, 0, stream>>>(x, perm, inv, cell64);
    k_mlp<<<nPtsBlocks, blk, 0, stream>>>(x, W1p, w2h, w2l, b2, (uint2*)feat);

    k_win32<<<kB * kChunks32, 1024, 0, stream>>>(x, inv, partial32);
    k_gather32<<<n32Blocks, blk, 0, stream>>>(partial32, perm, feat, out32);

    k_win64_out<<<kB * kSlabs64, 1024, 0, stream>>>(cell64, inv, feat, out64);
}